// Round 8
// baseline (490.171 us; speedup 1.0000x reference)
//
#include <hip/hip_runtime.h>
#include <hip/hip_bf16.h>

// Problem constants (fixed by reference): N=262144 rows, D=64, K=512 codes.
#define N_ROWS 262144
#define DIM 64
#define KC 512

// d_out layout — FLOAT32 (confirmed R2/R3/R7):
//   out[0]                      = loss
//   out[1 .. 1+N*D)             = quantized [N,64] row-major
//   out[1+N*D .. 1+N*D+N)       = float(encoding_indices)
//
// CORRECTNESS INVARIANT (R2..R7): replicate the reference's FLOAT32
// numerics exactly and decide the argmin in f32:
//   x_sq, e_sq : numpy pairwise sum (8-acc striped, squares rounded
//                separately, no FMA)
//   dot        : sequential fused-FMA chain, j ascending
//   d          : fl( fl(x_sq + e_sq_k) - 2*dot_k ), contraction off
//   argmin     : strict <, first-min-wins
// *** NO f64 override anywhere *** (f64 "safety nets" caused the 464.0
// failures in R2/R4/R5/R6 — near-ties are decided by the reference's own
// f32 rounding, and f64 truth disagrees on exactly those rows).
//
// PERF (R8): R3/R7 compiled to VGPR=40 + ~260MB scratch WRITE_SIZE — the
// float xr[64] alloca was never SROA-promoted (SROA runs before the
// #pragma unroll fires, so xr[j] is variable-indexed at promotion time).
// Fix: NO ARRAYS — the row is 16 named float4 variables; dot / sumsq /
// stores are macro-expanded over named vars in the identical FP order.

// ---- numpy pairwise sum of squares for n=64, array form (esq kernel) ----
__device__ __forceinline__ float np_sumsq64(const float* a) {
#pragma clang fp contract(off)
    float r[8];
#pragma unroll
    for (int j = 0; j < 8; ++j) r[j] = a[j] * a[j];
#pragma unroll
    for (int i = 8; i < 64; i += 8)
#pragma unroll
        for (int j = 0; j < 8; ++j) r[j] = r[j] + a[i + j] * a[i + j];
    return ((r[0] + r[1]) + (r[2] + r[3])) + ((r[4] + r[5]) + (r[6] + r[7]));
}

// ---- kernel 1: e_sq_k with numpy bit-exact summation ----
__global__ void esq_kernel(const float* __restrict__ cb, float* __restrict__ esq) {
    int k = blockIdx.x * blockDim.x + threadIdx.x;
    if (k < KC) esq[k] = np_sumsq64(cb + k * DIM);
}

// Striped square-sum chains over named vars, element index ascending —
// left-assoc '+' with contract(off) == numpy's sequential r[j] updates.
// r[j], j=0..3: elements j, j+8, ..., j+56 -> even vars, component j.
// r[j], j=4..7: odd vars, component j-4.
#define SUMSQ_EVEN(c) (X0.c*X0.c + X2.c*X2.c + X4.c*X4.c + X6.c*X6.c + \
                       X8.c*X8.c + X10.c*X10.c + X12.c*X12.c + X14.c*X14.c)
#define SUMSQ_ODD(c)  (X1.c*X1.c + X3.c*X3.c + X5.c*X5.c + X7.c*X7.c + \
                       X9.c*X9.c + X11.c*X11.c + X13.c*X13.c + X15.c*X15.c)

// 4 sequential fmaf steps of the dot chain (j ascending within the float4).
#define DOT4(E, X) \
    dot = fmaf((X).x, (E).x, dot); dot = fmaf((X).y, (E).y, dot); \
    dot = fmaf((X).z, (E).z, dot); dot = fmaf((X).w, (E).w, dot);

// ---- kernel 2: main VQ — one thread per row, row in 16 named float4s ----
__global__ __launch_bounds__(256, 4) void vq_kernel(
    const float* __restrict__ x, const float* __restrict__ cb,
    const float* __restrict__ esq, float* __restrict__ out,
    float* __restrict__ loss_acc)
{
    const int row = blockIdx.x * 256 + threadIdx.x;
    if (row >= N_ROWS) return;

    const float4* xv = reinterpret_cast<const float4*>(x + (size_t)row * DIM);
    float4 X0 = xv[0],  X1 = xv[1],  X2 = xv[2],  X3 = xv[3];
    float4 X4 = xv[4],  X5 = xv[5],  X6 = xv[6],  X7 = xv[7];
    float4 X8 = xv[8],  X9 = xv[9],  X10 = xv[10], X11 = xv[11];
    float4 X12 = xv[12], X13 = xv[13], X14 = xv[14], X15 = xv[15];

    // numpy-exact ||x||^2 on named vars (identical op order to np_sumsq64).
    float xsq;
    {
#pragma clang fp contract(off)
        float r0 = SUMSQ_EVEN(x), r1 = SUMSQ_EVEN(y);
        float r2 = SUMSQ_EVEN(z), r3 = SUMSQ_EVEN(w);
        float r4 = SUMSQ_ODD(x),  r5 = SUMSQ_ODD(y);
        float r6 = SUMSQ_ODD(z),  r7 = SUMSQ_ODD(w);
        xsq = ((r0 + r1) + (r2 + r3)) + ((r4 + r5) + (r6 + r7));
    }

    // Replicated reference distance; strict-< first-min-wins.
    float best = 3.4e38f;
    int bidx = 0;
#pragma unroll 2
    for (int k = 0; k < KC; ++k) {
        const float4* ev = reinterpret_cast<const float4*>(cb + (size_t)k * DIM);
        float4 E0 = ev[0],  E1 = ev[1],  E2 = ev[2],  E3 = ev[3];
        float4 E4 = ev[4],  E5 = ev[5],  E6 = ev[6],  E7 = ev[7];
        float4 E8 = ev[8],  E9 = ev[9],  E10 = ev[10], E11 = ev[11];
        float4 E12 = ev[12], E13 = ev[13], E14 = ev[14], E15 = ev[15];

        float dot = 0.f;                 // sequential fmaf chain, j = 0..63
        DOT4(E0, X0)   DOT4(E1, X1)   DOT4(E2, X2)   DOT4(E3, X3)
        DOT4(E4, X4)   DOT4(E5, X5)   DOT4(E6, X6)   DOT4(E7, X7)
        DOT4(E8, X8)   DOT4(E9, X9)   DOT4(E10, X10) DOT4(E11, X11)
        DOT4(E12, X12) DOT4(E13, X13) DOT4(E14, X14) DOT4(E15, X15)

        float d;
        {
#pragma clang fp contract(off)
            float t1 = xsq + esq[k];     // rounds (ufunc pass 1)
            d = t1 - 2.0f * dot;         // 2*dot exact; subtract rounds
        }
        if (d < best) { best = d; bidx = k; }
    }

    // quantized = codebook[bidx] (scalar dword stores: out+1 is only
    // 4B-aligned, float4 stores would be misaligned).
    const float* eb = cb + (size_t)bidx * DIM;
    float* q = out + 1 + (size_t)row * DIM;
#pragma unroll
    for (int j = 0; j < DIM; ++j) q[j] = eb[j];

    out[1 + (size_t)N_ROWS * DIM + row] = (float)bidx;

    // loss contribution: ||x - e||^2 = d_best
    float lrow = best;
#pragma unroll
    for (int off = 32; off > 0; off >>= 1) lrow += __shfl_down(lrow, off, 64);
    if ((threadIdx.x & 63) == 0) atomicAdd(loss_acc, lrow);
}

// ---- kernel 3: finalize loss ----
__global__ void fin_kernel(const float* __restrict__ loss_acc,
                           float* __restrict__ out) {
    if (threadIdx.x == 0) {
        float mean_sq = (*loss_acc) / (float)((size_t)N_ROWS * DIM);
        out[0] = 1.25f * mean_sq;  // q_loss + COMMITMENT_COST * e_loss
    }
}

extern "C" void kernel_launch(void* const* d_in, const int* in_sizes, int n_in,
                              void* d_out, int out_size, void* d_ws, size_t ws_size,
                              hipStream_t stream) {
    const float* x  = (const float*)d_in[0];
    const float* cb = (const float*)d_in[1];
    float* out = (float*)d_out;

    float* loss_acc = (float*)d_ws;                 // 4 B
    float* esq      = (float*)((char*)d_ws + 256);  // 512 f32 (2304 B total)

    hipMemsetAsync(d_ws, 0, 4, stream);             // zero loss accumulator
    esq_kernel<<<2, 256, 0, stream>>>(cb, esq);
    vq_kernel<<<N_ROWS / 256, 256, 0, stream>>>(x, cb, esq, out, loss_acc);
    fin_kernel<<<1, 64, 0, stream>>>(loss_acc, out);
}